// Round 4
// baseline (1064.698 us; speedup 1.0000x reference)
//
#include <hip/hip_runtime.h>
#include <hip/hip_bf16.h>
#include <math.h>

typedef float f32x4 __attribute__((ext_vector_type(4)));
typedef short s16x8 __attribute__((ext_vector_type(8)));

#define TSEQ 2048

__device__ __forceinline__ unsigned short f2bf(float f){
  unsigned int u = __builtin_bit_cast(unsigned int, f);
  u += 0x7FFFu + ((u >> 16) & 1u);
  return (unsigned short)(u >> 16);
}
__device__ __forceinline__ float sigf(float x){ return 1.0f / (1.0f + __expf(-x)); }
__device__ __forceinline__ float wredsum(float x){
  #pragma unroll
  for (int off = 32; off > 0; off >>= 1) x += __shfl_xor(x, off);
  return x;
}

// 16-lane-group sum via DPP (quad xor1, xor2, row_ror:4, row_ror:8) — no LDS.
template<int CTRL>
__device__ __forceinline__ float dpp_add(float x){
  int v = __builtin_amdgcn_update_dpp(0, __builtin_bit_cast(int, x), CTRL, 0xF, 0xF, true);
  return x + __builtin_bit_cast(float, v);
}
__device__ __forceinline__ float red16(float x){
  x = dpp_add<0xB1>(x);   // quad_perm [1,0,3,2]
  x = dpp_add<0x4E>(x);   // quad_perm [2,3,0,1]
  x = dpp_add<0x124>(x);  // row_ror:4
  x = dpp_add<0x128>(x);  // row_ror:8
  return x;
}

// ---------------- w0 prefix-scan (C=1024) ----------------
__global__ void w0_scan_k(const float* __restrict__ w0b, const float* __restrict__ w0d,
                          float* __restrict__ w0){
  __shared__ float buf[1024];
  int i = threadIdx.x;
  float v = 0.f;
  if (i > 0){
    float d = w0d[i-1];
    v = (d > 20.f) ? d : log1pf(__expf(d));   // softplus
  }
  buf[i] = v;
  __syncthreads();
  for (int off = 1; off < 1024; off <<= 1){
    float t = (i >= off) ? buf[i - off] : 0.f;
    __syncthreads();
    buf[i] += t;
    __syncthreads();
  }
  w0[i] = w0b[0] + buf[i];
}

// ---------------- bf16 MFMA GEMM: C[m,n] = sum_k A[m,k]*B[n,k] ----------------
#define A_MIX 0
#define A_BF16 1
#define EPI_F32 0
#define EPI_BF16 1
#define EPI_TANH_BF16 2
#define EPI_SIG_BF16 3
#define EPI_SIGBIAS_F32 4
#define EPI_DECAY_F32 5

template<int AMODE, int EPI>
__global__ __launch_bounds__(256) void gemm_k(
    const float* __restrict__ X, const float* __restrict__ MIXC,      // A_MIX source
    const unsigned short* __restrict__ ABF,                           // A_BF16 source
    const float* __restrict__ BW,                                     // weights (N,K) f32
    void* __restrict__ Cout,
    const float* __restrict__ bias, const float* __restrict__ w0,
    int M, int N, int K)
{
  __shared__ unsigned short As[128][40];
  __shared__ unsigned short Bs[128][40];
  const int tid  = threadIdx.x;
  const int m0   = blockIdx.y * 128;
  const int n0   = blockIdx.x * 128;
  const int row  = tid >> 1;
  const int c0   = (tid & 1) << 4;
  const int lane = tid & 63;
  const int wv   = tid >> 6;
  const int wr   = (wv >> 1) << 6;
  const int wc   = (wv & 1) << 6;
  const int lr   = lane & 15;
  const int lg   = lane >> 4;

  f32x4 acc[4][4];
  #pragma unroll
  for (int i = 0; i < 4; i++)
    #pragma unroll
    for (int j = 0; j < 4; j++) acc[i][j] = f32x4{0.f, 0.f, 0.f, 0.f};

  for (int k0 = 0; k0 < K; k0 += 32){
    // ---- stage A (16 bf16 per thread) ----
    s16x8 a_lo, a_hi;
    if constexpr (AMODE == A_MIX){
      const int gm = m0 + row;
      const float* xr = X + (size_t)gm * K + (k0 + c0);
      float xv[16], sv[16], mv[16];
      #pragma unroll
      for (int i = 0; i < 4; i++){
        f32x4 q = *(const f32x4*)(xr + i*4);
        xv[4*i+0]=q.x; xv[4*i+1]=q.y; xv[4*i+2]=q.z; xv[4*i+3]=q.w;
      }
      if ((gm & (TSEQ - 1)) != 0){
        const float* xs = xr - K;
        #pragma unroll
        for (int i = 0; i < 4; i++){
          f32x4 q = *(const f32x4*)(xs + i*4);
          sv[4*i+0]=q.x; sv[4*i+1]=q.y; sv[4*i+2]=q.z; sv[4*i+3]=q.w;
        }
      } else {
        #pragma unroll
        for (int i = 0; i < 16; i++) sv[i] = 0.f;   // time_shift row 0 = zeros
      }
      const float* mc = MIXC + (k0 + c0);
      #pragma unroll
      for (int i = 0; i < 4; i++){
        f32x4 q = *(const f32x4*)(mc + i*4);
        mv[4*i+0]=q.x; mv[4*i+1]=q.y; mv[4*i+2]=q.z; mv[4*i+3]=q.w;
      }
      #pragma unroll
      for (int i = 0; i < 8; i++){
        float v0 = xv[i] + (sv[i] - xv[i]) * mv[i];
        a_lo[i] = (short)f2bf(v0);
      }
      #pragma unroll
      for (int i = 0; i < 8; i++){
        float v0 = xv[8+i] + (sv[8+i] - xv[8+i]) * mv[8+i];
        a_hi[i] = (short)f2bf(v0);
      }
    } else {
      const unsigned short* ar = ABF + (size_t)(m0 + row) * K + (k0 + c0);
      a_lo = *(const s16x8*)ar;
      a_hi = *(const s16x8*)(ar + 8);
    }
    // ---- stage B (convert f32 weights) ----
    s16x8 b_lo, b_hi;
    const int gn = n0 + row;
    if (gn < N){
      const float* br = BW + (size_t)gn * K + (k0 + c0);
      f32x4 q0 = *(const f32x4*)(br + 0);
      f32x4 q1 = *(const f32x4*)(br + 4);
      f32x4 q2 = *(const f32x4*)(br + 8);
      f32x4 q3 = *(const f32x4*)(br + 12);
      b_lo[0]=(short)f2bf(q0.x); b_lo[1]=(short)f2bf(q0.y); b_lo[2]=(short)f2bf(q0.z); b_lo[3]=(short)f2bf(q0.w);
      b_lo[4]=(short)f2bf(q1.x); b_lo[5]=(short)f2bf(q1.y); b_lo[6]=(short)f2bf(q1.z); b_lo[7]=(short)f2bf(q1.w);
      b_hi[0]=(short)f2bf(q2.x); b_hi[1]=(short)f2bf(q2.y); b_hi[2]=(short)f2bf(q2.z); b_hi[3]=(short)f2bf(q2.w);
      b_hi[4]=(short)f2bf(q3.x); b_hi[5]=(short)f2bf(q3.y); b_hi[6]=(short)f2bf(q3.z); b_hi[7]=(short)f2bf(q3.w);
    } else {
      b_lo = s16x8{0,0,0,0,0,0,0,0};
      b_hi = s16x8{0,0,0,0,0,0,0,0};
    }
    *(s16x8*)&As[row][c0]   = a_lo;
    *(s16x8*)&As[row][c0+8] = a_hi;
    *(s16x8*)&Bs[row][c0]   = b_lo;
    *(s16x8*)&Bs[row][c0+8] = b_hi;
    __syncthreads();
    // ---- MFMA ----
    s16x8 af[4], bfr[4];
    #pragma unroll
    for (int i = 0; i < 4; i++) af[i]  = *(const s16x8*)&As[wr + i*16 + lr][lg*8];
    #pragma unroll
    for (int j = 0; j < 4; j++) bfr[j] = *(const s16x8*)&Bs[wc + j*16 + lr][lg*8];
    #pragma unroll
    for (int i = 0; i < 4; i++)
      #pragma unroll
      for (int j = 0; j < 4; j++)
        acc[i][j] = __builtin_amdgcn_mfma_f32_16x16x32_bf16(af[i], bfr[j], acc[i][j], 0, 0, 0);
    __syncthreads();
  }
  // ---- epilogue: D row=(lane>>4)*4+q, col=lane&15 ----
  #pragma unroll
  for (int i = 0; i < 4; i++){
    const int mb = m0 + wr + i*16 + lg*4;
    #pragma unroll
    for (int j = 0; j < 4; j++){
      const int n = n0 + wc + j*16 + lr;
      if (n < N){
        #pragma unroll
        for (int q = 0; q < 4; q++){
          const int m = mb + q;
          const float val = acc[i][j][q];
          const size_t oix = (size_t)m * N + n;
          if constexpr (EPI == EPI_F32)            ((float*)Cout)[oix] = val;
          else if constexpr (EPI == EPI_BF16)      ((unsigned short*)Cout)[oix] = f2bf(val);
          else if constexpr (EPI == EPI_TANH_BF16) ((unsigned short*)Cout)[oix] = f2bf(tanhf(val));
          else if constexpr (EPI == EPI_SIG_BF16)  ((unsigned short*)Cout)[oix] = f2bf(sigf(val));
          else if constexpr (EPI == EPI_SIGBIAS_F32) ((float*)Cout)[oix] = sigf(val + bias[n]);
          else if constexpr (EPI == EPI_DECAY_F32){
            float z = val + bias[n] + w0[n];
            ((float*)Cout)[oix] = expf(-0.60653065971263342f * sigf(z));
          }
        }
      }
    }
  }
}

// ---------------- kk normalize, k scale, b = kk*a (in place over a) ----------------
__global__ __launch_bounds__(256) void kkprep_k(
    float* __restrict__ k, float* __restrict__ ab, float* __restrict__ kk,
    const float* __restrict__ kkc, const float* __restrict__ kac)
{
  const int row  = blockIdx.x * 4 + (threadIdx.x >> 6);
  const int lane = threadIdx.x & 63;
  const size_t idx = (size_t)row * 64 + lane;
  const int c = ((row & 15) << 6) + lane;
  const float kv = k[idx];
  const float av = ab[idx];
  const float t  = kv * kkc[c];
  const float ss = wredsum(t * t);
  const float kkv = t / fmaxf(sqrtf(ss), 1e-12f);
  kk[idx] = kkv;
  k[idx]  = kv * (1.f + (av - 1.f) * kac[c]);
  ab[idx] = kkv * av;     // b_in
}

// ---------------- RWKV-7 scan: row-parallel, 512 waves ----------------
// Wave handles 4 rows of one (b,h): lane = (g,L), g=lane>>4 selects row,
// L=lane&15 selects k-quad (k = 4L..4L+3). State = 4 VGPRs per lane.
// Reductions are 16-lane DPP sums. No LDS, no barriers.
__global__ __launch_bounds__(64) void scan_k(
    const float* __restrict__ r, const float* __restrict__ w, const float* __restrict__ k,
    const float* __restrict__ v, const float* __restrict__ b, const float* __restrict__ kk,
    float* __restrict__ o)
{
  const int lane = threadIdx.x;
  const int L    = lane & 15;
  const int g    = lane >> 4;
  const int bh   = blockIdx.x & 31;            // b*16+h
  const int grp  = blockIdx.x >> 5;            // 0..15 row group
  const int bb   = bh >> 4, hh = bh & 15;
  const int rowb = grp * 4;
  const size_t base = (size_t)bb * TSEQ * 1024 + hh * 64;

  size_t vofs = base + 4 * L;          // float4 element base for vectors
  size_t sofs = base + rowb + g;       // scalar element for v / o

  f32x4 S = {0.f, 0.f, 0.f, 0.f};

  f32x4 cr = *(const f32x4*)(r + vofs);
  f32x4 cw = *(const f32x4*)(w + vofs);
  f32x4 ck = *(const f32x4*)(k + vofs);
  f32x4 cb = *(const f32x4*)(b + vofs);
  f32x4 ca = *(const f32x4*)(kk + vofs);
  float cv = v[sofs];

  for (int t = 0; t < TSEQ; ++t){
    f32x4 nr, nw, nk, nb, na; float nv = 0.f;
    if (t + 1 < TSEQ){
      const size_t nvo = vofs + 1024, nso = sofs + 1024;
      nr = *(const f32x4*)(r + nvo);
      nw = *(const f32x4*)(w + nvo);
      nk = *(const f32x4*)(k + nvo);
      nb = *(const f32x4*)(b + nvo);
      na = *(const f32x4*)(kk + nvo);
      nv = v[nso];
    } else {
      nr = nw = nk = nb = na = f32x4{0.f,0.f,0.f,0.f};
    }
    // sa = sum_k S[row][k] * (-kk[k])
    float p = S.x * ca.x;
    p = fmaf(S.y, ca.y, p);
    p = fmaf(S.z, ca.z, p);
    p = fmaf(S.w, ca.w, p);
    const float sa = -red16(p);
    // S = S*w + sa*b + v*k
    S.x = fmaf(S.x, cw.x, fmaf(sa, cb.x, cv * ck.x));
    S.y = fmaf(S.y, cw.y, fmaf(sa, cb.y, cv * ck.y));
    S.z = fmaf(S.z, cw.z, fmaf(sa, cb.z, cv * ck.z));
    S.w = fmaf(S.w, cw.w, fmaf(sa, cb.w, cv * ck.w));
    // o = sum_k S[row][k] * r[k]
    float q = S.x * cr.x;
    q = fmaf(S.y, cr.y, q);
    q = fmaf(S.z, cr.z, q);
    q = fmaf(S.w, cr.w, q);
    const float oo = red16(q);
    if (L == 0) o[sofs] = oo;
    vofs += 1024; sofs += 1024;
    cr = nr; cw = nw; ck = nk; cb = nb; ca = na; cv = nv;
  }
}

// ---------------- GroupNorm + bonus + gate -> y (bf16) ----------------
__global__ __launch_bounds__(256) void gnout_k(
    const float* __restrict__ o, const float* __restrict__ r, const float* __restrict__ k,
    const float* __restrict__ v, const float* __restrict__ g,
    const float* __restrict__ rk, const float* __restrict__ gnw, const float* __restrict__ gnb,
    unsigned short* __restrict__ y)
{
  const int row  = blockIdx.x * 4 + (threadIdx.x >> 6);
  const int lane = threadIdx.x & 63;
  const size_t idx = (size_t)row * 64 + lane;
  const int c = ((row & 15) << 6) + lane;
  const float ov  = o[idx];
  const float mu  = wredsum(ov) * 0.015625f;
  const float d   = ov - mu;
  const float var = wredsum(d * d) * 0.015625f;
  const float on  = d * rsqrtf(var + 6.4e-4f) * gnw[c] + gnb[c];   // eps = D*1e-5
  const float s   = wredsum(r[idx] * k[idx] * rk[c]);
  const float yv  = (on + s * v[idx]) * g[idx];
  y[idx] = f2bf(yv);
}

extern "C" void kernel_launch(void* const* d_in, const int* in_sizes, int n_in,
                              void* d_out, int out_size, void* d_ws, size_t ws_size,
                              hipStream_t stream)
{
  const float* x    = (const float*)d_in[0];
  const float* x_r  = (const float*)d_in[1];
  const float* x_w  = (const float*)d_in[2];
  const float* x_k  = (const float*)d_in[3];
  const float* x_v  = (const float*)d_in[4];
  const float* x_a  = (const float*)d_in[5];
  const float* x_g  = (const float*)d_in[6];
  const float* k_k  = (const float*)d_in[7];
  const float* k_a  = (const float*)d_in[8];
  const float* r_k  = (const float*)d_in[9];
  const float* Wr   = (const float*)d_in[10];
  const float* Wk   = (const float*)d_in[11];
  const float* Wv   = (const float*)d_in[12];
  const float* Wo   = (const float*)d_in[13];
  const float* wA   = (const float*)d_in[14];
  const float* wB   = (const float*)d_in[15];
  const float* wbias= (const float*)d_in[16];
  const float* aA   = (const float*)d_in[17];
  const float* aB   = (const float*)d_in[18];
  const float* abias= (const float*)d_in[19];
  const float* gA   = (const float*)d_in[20];
  const float* gB   = (const float*)d_in[21];
  const float* gnw  = (const float*)d_in[22];
  const float* gnb  = (const float*)d_in[23];
  const float* w0b  = (const float*)d_in[24];
  const float* w0d  = (const float*)d_in[25];

  char* ws = (char*)d_ws;
  const size_t MB = 1024ull * 1024ull;
  float* r_  = (float*)(ws +   0*MB);
  float* k_  = (float*)(ws +  16*MB);
  float* v_  = (float*)(ws +  32*MB);
  float* wd_ = (float*)(ws +  48*MB);   // decay
  float* ab_ = (float*)(ws +  64*MB);   // a, then b (in place)
  float* kk_ = (float*)(ws +  80*MB);
  float* o_  = (float*)(ws +  96*MB);
  float* g_  = (float*)(ws + 112*MB);
  unsigned short* y_   = (unsigned short*)(ws + 128*MB);
  unsigned short* wl1_ = (unsigned short*)(ws + 136*MB);
  unsigned short* al1_ = (unsigned short*)(ws + 137*MB);
  unsigned short* gl1_ = (unsigned short*)(ws + 138*MB);
  float* w0_ = (float*)(ws + 140*MB);

  const dim3 blk(256);
  const dim3 gBig(8, 32), gN64(1, 32), gN160(2, 32);

  w0_scan_k<<<dim3(1), dim3(1024), 0, stream>>>(w0b, w0d, w0_);

  // r, k, v projections (token-shift mix fused into A staging)
  gemm_k<A_MIX, EPI_F32><<<gBig, blk, 0, stream>>>(x, x_r, nullptr, Wr, r_, nullptr, nullptr, 4096, 1024, 1024);
  gemm_k<A_MIX, EPI_F32><<<gBig, blk, 0, stream>>>(x, x_k, nullptr, Wk, k_, nullptr, nullptr, 4096, 1024, 1024);
  gemm_k<A_MIX, EPI_F32><<<gBig, blk, 0, stream>>>(x, x_v, nullptr, Wv, v_, nullptr, nullptr, 4096, 1024, 1024);

  // decay LoRA: tanh(xw@A^T) -> @B^T + bias + w0 -> decay
  gemm_k<A_MIX, EPI_TANH_BF16><<<gN64, blk, 0, stream>>>(x, x_w, nullptr, wA, wl1_, nullptr, nullptr, 4096, 64, 1024);
  gemm_k<A_BF16, EPI_DECAY_F32><<<gBig, blk, 0, stream>>>(nullptr, nullptr, wl1_, wB, wd_, wbias, w0_, 4096, 1024, 64);

  // a LoRA: (xa@A^T) -> sigmoid(@B^T + bias)
  gemm_k<A_MIX, EPI_BF16><<<gN64, blk, 0, stream>>>(x, x_a, nullptr, aA, al1_, nullptr, nullptr, 4096, 64, 1024);
  gemm_k<A_BF16, EPI_SIGBIAS_F32><<<gBig, blk, 0, stream>>>(nullptr, nullptr, al1_, aB, ab_, abias, nullptr, 4096, 1024, 64);

  // g LoRA: sigmoid(xg@A^T) -> @B^T
  gemm_k<A_MIX, EPI_SIG_BF16><<<gN160, blk, 0, stream>>>(x, x_g, nullptr, gA, gl1_, nullptr, nullptr, 4096, 160, 1024);
  gemm_k<A_BF16, EPI_F32><<<gBig, blk, 0, stream>>>(nullptr, nullptr, gl1_, gB, g_, nullptr, nullptr, 4096, 1024, 160);

  // kk normalize + k scale + b
  kkprep_k<<<dim3(16384), blk, 0, stream>>>(k_, ab_, kk_, k_k, k_a);

  // sequential recurrence (row-parallel: 512 waves)
  scan_k<<<dim3(512), dim3(64), 0, stream>>>(r_, wd_, k_, v_, ab_, kk_, o_);

  // GroupNorm + bonus + gate
  gnout_k<<<dim3(16384), blk, 0, stream>>>(o_, r_, k_, v_, g_, r_k, gnw, gnb, y_);

  // output projection
  gemm_k<A_BF16, EPI_F32><<<gBig, blk, 0, stream>>>(nullptr, nullptr, y_, Wo, (float*)d_out, nullptr, nullptr, 4096, 1024, 1024);
}

// Round 5
// 772.712 us; speedup vs baseline: 1.3779x; 1.3779x over previous
//
#include <hip/hip_runtime.h>
#include <hip/hip_bf16.h>
#include <math.h>

typedef float f32x4 __attribute__((ext_vector_type(4)));
typedef short s16x8 __attribute__((ext_vector_type(8)));

#define TSEQ 2048

__device__ __forceinline__ unsigned short f2bf(float f){
  unsigned int u = __builtin_bit_cast(unsigned int, f);
  u += 0x7FFFu + ((u >> 16) & 1u);
  return (unsigned short)(u >> 16);
}
__device__ __forceinline__ float sigf(float x){ return 1.0f / (1.0f + __expf(-x)); }
__device__ __forceinline__ float wredsum(float x){
  #pragma unroll
  for (int off = 32; off > 0; off >>= 1) x += __shfl_xor(x, off);
  return x;
}

// 16-lane-group sum via DPP (quad xor1, xor2, row_ror:4, row_ror:8) — no LDS.
template<int CTRL>
__device__ __forceinline__ float dpp_add(float x){
  int v = __builtin_amdgcn_update_dpp(0, __builtin_bit_cast(int, x), CTRL, 0xF, 0xF, true);
  return x + __builtin_bit_cast(float, v);
}
__device__ __forceinline__ float red16(float x){
  x = dpp_add<0xB1>(x);   // quad_perm [1,0,3,2]
  x = dpp_add<0x4E>(x);   // quad_perm [2,3,0,1]
  x = dpp_add<0x124>(x);  // row_ror:4
  x = dpp_add<0x128>(x);  // row_ror:8
  return x;
}

// ---------------- w0 prefix-scan (C=1024) ----------------
__global__ void w0_scan_k(const float* __restrict__ w0b, const float* __restrict__ w0d,
                          float* __restrict__ w0){
  __shared__ float buf[1024];
  int i = threadIdx.x;
  float v = 0.f;
  if (i > 0){
    float d = w0d[i-1];
    v = (d > 20.f) ? d : log1pf(__expf(d));   // softplus
  }
  buf[i] = v;
  __syncthreads();
  for (int off = 1; off < 1024; off <<= 1){
    float t = (i >= off) ? buf[i - off] : 0.f;
    __syncthreads();
    buf[i] += t;
    __syncthreads();
  }
  w0[i] = w0b[0] + buf[i];
}

// ---------------- bf16 MFMA GEMM: C[m,n] = sum_k A[m,k]*B[n,k] ----------------
#define A_MIX 0
#define A_BF16 1
#define EPI_F32 0
#define EPI_BF16 1
#define EPI_TANH_BF16 2
#define EPI_SIG_BF16 3
#define EPI_SIGBIAS_F32 4
#define EPI_DECAY_F32 5

template<int AMODE, int EPI>
__global__ __launch_bounds__(256) void gemm_k(
    const float* __restrict__ X, const float* __restrict__ MIXC,      // A_MIX source
    const unsigned short* __restrict__ ABF,                           // A_BF16 source
    const float* __restrict__ BW,                                     // weights (N,K) f32
    void* __restrict__ Cout,
    const float* __restrict__ bias, const float* __restrict__ w0,
    int M, int N, int K)
{
  __shared__ unsigned short As[128][40];
  __shared__ unsigned short Bs[128][40];
  const int tid  = threadIdx.x;
  const int m0   = blockIdx.y * 128;
  const int n0   = blockIdx.x * 128;
  const int row  = tid >> 1;
  const int c0   = (tid & 1) << 4;
  const int lane = tid & 63;
  const int wv   = tid >> 6;
  const int wr   = (wv >> 1) << 6;
  const int wc   = (wv & 1) << 6;
  const int lr   = lane & 15;
  const int lg   = lane >> 4;

  f32x4 acc[4][4];
  #pragma unroll
  for (int i = 0; i < 4; i++)
    #pragma unroll
    for (int j = 0; j < 4; j++) acc[i][j] = f32x4{0.f, 0.f, 0.f, 0.f};

  for (int k0 = 0; k0 < K; k0 += 32){
    // ---- stage A (16 bf16 per thread) ----
    s16x8 a_lo, a_hi;
    if constexpr (AMODE == A_MIX){
      const int gm = m0 + row;
      const float* xr = X + (size_t)gm * K + (k0 + c0);
      float xv[16], sv[16], mv[16];
      #pragma unroll
      for (int i = 0; i < 4; i++){
        f32x4 q = *(const f32x4*)(xr + i*4);
        xv[4*i+0]=q.x; xv[4*i+1]=q.y; xv[4*i+2]=q.z; xv[4*i+3]=q.w;
      }
      if ((gm & (TSEQ - 1)) != 0){
        const float* xs = xr - K;
        #pragma unroll
        for (int i = 0; i < 4; i++){
          f32x4 q = *(const f32x4*)(xs + i*4);
          sv[4*i+0]=q.x; sv[4*i+1]=q.y; sv[4*i+2]=q.z; sv[4*i+3]=q.w;
        }
      } else {
        #pragma unroll
        for (int i = 0; i < 16; i++) sv[i] = 0.f;   // time_shift row 0 = zeros
      }
      const float* mc = MIXC + (k0 + c0);
      #pragma unroll
      for (int i = 0; i < 4; i++){
        f32x4 q = *(const f32x4*)(mc + i*4);
        mv[4*i+0]=q.x; mv[4*i+1]=q.y; mv[4*i+2]=q.z; mv[4*i+3]=q.w;
      }
      #pragma unroll
      for (int i = 0; i < 8; i++){
        float v0 = xv[i] + (sv[i] - xv[i]) * mv[i];
        a_lo[i] = (short)f2bf(v0);
      }
      #pragma unroll
      for (int i = 0; i < 8; i++){
        float v0 = xv[8+i] + (sv[8+i] - xv[8+i]) * mv[8+i];
        a_hi[i] = (short)f2bf(v0);
      }
    } else {
      const unsigned short* ar = ABF + (size_t)(m0 + row) * K + (k0 + c0);
      a_lo = *(const s16x8*)ar;
      a_hi = *(const s16x8*)(ar + 8);
    }
    // ---- stage B (convert f32 weights) ----
    s16x8 b_lo, b_hi;
    const int gn = n0 + row;
    if (gn < N){
      const float* br = BW + (size_t)gn * K + (k0 + c0);
      f32x4 q0 = *(const f32x4*)(br + 0);
      f32x4 q1 = *(const f32x4*)(br + 4);
      f32x4 q2 = *(const f32x4*)(br + 8);
      f32x4 q3 = *(const f32x4*)(br + 12);
      b_lo[0]=(short)f2bf(q0.x); b_lo[1]=(short)f2bf(q0.y); b_lo[2]=(short)f2bf(q0.z); b_lo[3]=(short)f2bf(q0.w);
      b_lo[4]=(short)f2bf(q1.x); b_lo[5]=(short)f2bf(q1.y); b_lo[6]=(short)f2bf(q1.z); b_lo[7]=(short)f2bf(q1.w);
      b_hi[0]=(short)f2bf(q2.x); b_hi[1]=(short)f2bf(q2.y); b_hi[2]=(short)f2bf(q2.z); b_hi[3]=(short)f2bf(q2.w);
      b_hi[4]=(short)f2bf(q3.x); b_hi[5]=(short)f2bf(q3.y); b_hi[6]=(short)f2bf(q3.z); b_hi[7]=(short)f2bf(q3.w);
    } else {
      b_lo = s16x8{0,0,0,0,0,0,0,0};
      b_hi = s16x8{0,0,0,0,0,0,0,0};
    }
    *(s16x8*)&As[row][c0]   = a_lo;
    *(s16x8*)&As[row][c0+8] = a_hi;
    *(s16x8*)&Bs[row][c0]   = b_lo;
    *(s16x8*)&Bs[row][c0+8] = b_hi;
    __syncthreads();
    // ---- MFMA ----
    s16x8 af[4], bfr[4];
    #pragma unroll
    for (int i = 0; i < 4; i++) af[i]  = *(const s16x8*)&As[wr + i*16 + lr][lg*8];
    #pragma unroll
    for (int j = 0; j < 4; j++) bfr[j] = *(const s16x8*)&Bs[wc + j*16 + lr][lg*8];
    #pragma unroll
    for (int i = 0; i < 4; i++)
      #pragma unroll
      for (int j = 0; j < 4; j++)
        acc[i][j] = __builtin_amdgcn_mfma_f32_16x16x32_bf16(af[i], bfr[j], acc[i][j], 0, 0, 0);
    __syncthreads();
  }
  // ---- epilogue: D row=(lane>>4)*4+q, col=lane&15 ----
  #pragma unroll
  for (int i = 0; i < 4; i++){
    const int mb = m0 + wr + i*16 + lg*4;
    #pragma unroll
    for (int j = 0; j < 4; j++){
      const int n = n0 + wc + j*16 + lr;
      if (n < N){
        #pragma unroll
        for (int q = 0; q < 4; q++){
          const int m = mb + q;
          const float val = acc[i][j][q];
          const size_t oix = (size_t)m * N + n;
          if constexpr (EPI == EPI_F32)            ((float*)Cout)[oix] = val;
          else if constexpr (EPI == EPI_BF16)      ((unsigned short*)Cout)[oix] = f2bf(val);
          else if constexpr (EPI == EPI_TANH_BF16) ((unsigned short*)Cout)[oix] = f2bf(tanhf(val));
          else if constexpr (EPI == EPI_SIG_BF16)  ((unsigned short*)Cout)[oix] = f2bf(sigf(val));
          else if constexpr (EPI == EPI_SIGBIAS_F32) ((float*)Cout)[oix] = sigf(val + bias[n]);
          else if constexpr (EPI == EPI_DECAY_F32){
            float z = val + bias[n] + w0[n];
            ((float*)Cout)[oix] = expf(-0.60653065971263342f * sigf(z));
          }
        }
      }
    }
  }
}

// ---------------- kk normalize, k scale, b = kk*a (in place over a) ----------------
__global__ __launch_bounds__(256) void kkprep_k(
    float* __restrict__ k, float* __restrict__ ab, float* __restrict__ kk,
    const float* __restrict__ kkc, const float* __restrict__ kac)
{
  const int row  = blockIdx.x * 4 + (threadIdx.x >> 6);
  const int lane = threadIdx.x & 63;
  const size_t idx = (size_t)row * 64 + lane;
  const int c = ((row & 15) << 6) + lane;
  const float kv = k[idx];
  const float av = ab[idx];
  const float t  = kv * kkc[c];
  const float ss = wredsum(t * t);
  const float kkv = t / fmaxf(sqrtf(ss), 1e-12f);
  kk[idx] = kkv;
  k[idx]  = kv * (1.f + (av - 1.f) * kac[c]);
  ab[idx] = kkv * av;     // b_in
}

// ---------------- RWKV-7 scan: row-parallel, depth-8 software pipeline ----------------
// Wave handles 4 rows of one (b,h): lane = (g,L), g=lane>>4 selects row,
// L=lane&15 selects k-quad (k = 4L..4L+3). State = 4 VGPRs per lane.
// Reductions are 16-lane DPP sums. No LDS, no barriers.
// P=8 register buffers: loads issued 8 steps ahead of use (~880 cyc cover
// vs ~750 cyc observed latency). All buffer indices compile-time (unrolled).
#define PDEPTH 8
__global__ __launch_bounds__(64) void scan_k(
    const float* __restrict__ r, const float* __restrict__ w, const float* __restrict__ k,
    const float* __restrict__ v, const float* __restrict__ b, const float* __restrict__ kk,
    float* __restrict__ o)
{
  const int lane = threadIdx.x;
  const int L    = lane & 15;
  const int g    = lane >> 4;
  const int bh   = blockIdx.x & 31;            // b*16+h
  const int grp  = blockIdx.x >> 5;            // 0..15 row group
  const int bb   = bh >> 4, hh = bh & 15;
  const int rowb = grp * 4;
  const size_t base = (size_t)bb * TSEQ * 1024 + hh * 64;

  const size_t vofs = base + 4 * L;    // float4 element base for vectors
  const size_t sofs = base + rowb + g; // scalar element for v / o

  f32x4 S = {0.f, 0.f, 0.f, 0.f};

  f32x4 R[PDEPTH], W[PDEPTH], K[PDEPTH], Bv[PDEPTH], A[PDEPTH];
  float Vv[PDEPTH];

  size_t lvo = vofs, lso = sofs;       // next-load offsets
  #pragma unroll
  for (int i = 0; i < PDEPTH; i++){
    R[i]  = *(const f32x4*)(r  + lvo);
    W[i]  = *(const f32x4*)(w  + lvo);
    K[i]  = *(const f32x4*)(k  + lvo);
    Bv[i] = *(const f32x4*)(b  + lvo);
    A[i]  = *(const f32x4*)(kk + lvo);
    Vv[i] = v[lso];
    lvo += 1024; lso += 1024;
  }

  size_t sto = sofs;                   // store offset
  for (int t = 0; t < TSEQ; t += PDEPTH){
    const bool refill = (t <= TSEQ - 2*PDEPTH);
    #pragma unroll
    for (int i = 0; i < PDEPTH; i++){
      // sa = sum_k S[row][k] * (-kk[k])
      float p = S.x * A[i].x;
      p = fmaf(S.y, A[i].y, p);
      p = fmaf(S.z, A[i].z, p);
      p = fmaf(S.w, A[i].w, p);
      const float sa = -red16(p);
      const float cv = Vv[i];
      // S = S*w + sa*b + v*k
      S.x = fmaf(S.x, W[i].x, fmaf(sa, Bv[i].x, cv * K[i].x));
      S.y = fmaf(S.y, W[i].y, fmaf(sa, Bv[i].y, cv * K[i].y));
      S.z = fmaf(S.z, W[i].z, fmaf(sa, Bv[i].z, cv * K[i].z));
      S.w = fmaf(S.w, W[i].w, fmaf(sa, Bv[i].w, cv * K[i].w));
      // o = sum_k S[row][k] * r[k]
      float q = S.x * R[i].x;
      q = fmaf(S.y, R[i].y, q);
      q = fmaf(S.z, R[i].z, q);
      q = fmaf(S.w, R[i].w, q);
      const float oo = red16(q);
      if (L == 0) o[sto] = oo;
      sto += 1024;
      // refill buffer i with step t+i+PDEPTH
      if (refill){
        R[i]  = *(const f32x4*)(r  + lvo);
        W[i]  = *(const f32x4*)(w  + lvo);
        K[i]  = *(const f32x4*)(k  + lvo);
        Bv[i] = *(const f32x4*)(b  + lvo);
        A[i]  = *(const f32x4*)(kk + lvo);
        Vv[i] = v[lso];
        lvo += 1024; lso += 1024;
      }
    }
  }
}

// ---------------- GroupNorm + bonus + gate -> y (bf16) ----------------
__global__ __launch_bounds__(256) void gnout_k(
    const float* __restrict__ o, const float* __restrict__ r, const float* __restrict__ k,
    const float* __restrict__ v, const float* __restrict__ g,
    const float* __restrict__ rk, const float* __restrict__ gnw, const float* __restrict__ gnb,
    unsigned short* __restrict__ y)
{
  const int row  = blockIdx.x * 4 + (threadIdx.x >> 6);
  const int lane = threadIdx.x & 63;
  const size_t idx = (size_t)row * 64 + lane;
  const int c = ((row & 15) << 6) + lane;
  const float ov  = o[idx];
  const float mu  = wredsum(ov) * 0.015625f;
  const float d   = ov - mu;
  const float var = wredsum(d * d) * 0.015625f;
  const float on  = d * rsqrtf(var + 6.4e-4f) * gnw[c] + gnb[c];   // eps = D*1e-5
  const float s   = wredsum(r[idx] * k[idx] * rk[c]);
  const float yv  = (on + s * v[idx]) * g[idx];
  y[idx] = f2bf(yv);
}

extern "C" void kernel_launch(void* const* d_in, const int* in_sizes, int n_in,
                              void* d_out, int out_size, void* d_ws, size_t ws_size,
                              hipStream_t stream)
{
  const float* x    = (const float*)d_in[0];
  const float* x_r  = (const float*)d_in[1];
  const float* x_w  = (const float*)d_in[2];
  const float* x_k  = (const float*)d_in[3];
  const float* x_v  = (const float*)d_in[4];
  const float* x_a  = (const float*)d_in[5];
  const float* x_g  = (const float*)d_in[6];
  const float* k_k  = (const float*)d_in[7];
  const float* k_a  = (const float*)d_in[8];
  const float* r_k  = (const float*)d_in[9];
  const float* Wr   = (const float*)d_in[10];
  const float* Wk   = (const float*)d_in[11];
  const float* Wv   = (const float*)d_in[12];
  const float* Wo   = (const float*)d_in[13];
  const float* wA   = (const float*)d_in[14];
  const float* wB   = (const float*)d_in[15];
  const float* wbias= (const float*)d_in[16];
  const float* aA   = (const float*)d_in[17];
  const float* aB   = (const float*)d_in[18];
  const float* abias= (const float*)d_in[19];
  const float* gA   = (const float*)d_in[20];
  const float* gB   = (const float*)d_in[21];
  const float* gnw  = (const float*)d_in[22];
  const float* gnb  = (const float*)d_in[23];
  const float* w0b  = (const float*)d_in[24];
  const float* w0d  = (const float*)d_in[25];

  char* ws = (char*)d_ws;
  const size_t MB = 1024ull * 1024ull;
  float* r_  = (float*)(ws +   0*MB);
  float* k_  = (float*)(ws +  16*MB);
  float* v_  = (float*)(ws +  32*MB);
  float* wd_ = (float*)(ws +  48*MB);   // decay
  float* ab_ = (float*)(ws +  64*MB);   // a, then b (in place)
  float* kk_ = (float*)(ws +  80*MB);
  float* o_  = (float*)(ws +  96*MB);
  float* g_  = (float*)(ws + 112*MB);
  unsigned short* y_   = (unsigned short*)(ws + 128*MB);
  unsigned short* wl1_ = (unsigned short*)(ws + 136*MB);
  unsigned short* al1_ = (unsigned short*)(ws + 137*MB);
  unsigned short* gl1_ = (unsigned short*)(ws + 138*MB);
  float* w0_ = (float*)(ws + 140*MB);

  const dim3 blk(256);
  const dim3 gBig(8, 32), gN64(1, 32), gN160(2, 32);

  w0_scan_k<<<dim3(1), dim3(1024), 0, stream>>>(w0b, w0d, w0_);

  // r, k, v projections (token-shift mix fused into A staging)
  gemm_k<A_MIX, EPI_F32><<<gBig, blk, 0, stream>>>(x, x_r, nullptr, Wr, r_, nullptr, nullptr, 4096, 1024, 1024);
  gemm_k<A_MIX, EPI_F32><<<gBig, blk, 0, stream>>>(x, x_k, nullptr, Wk, k_, nullptr, nullptr, 4096, 1024, 1024);
  gemm_k<A_MIX, EPI_F32><<<gBig, blk, 0, stream>>>(x, x_v, nullptr, Wv, v_, nullptr, nullptr, 4096, 1024, 1024);

  // decay LoRA: tanh(xw@A^T) -> @B^T + bias + w0 -> decay
  gemm_k<A_MIX, EPI_TANH_BF16><<<gN64, blk, 0, stream>>>(x, x_w, nullptr, wA, wl1_, nullptr, nullptr, 4096, 64, 1024);
  gemm_k<A_BF16, EPI_DECAY_F32><<<gBig, blk, 0, stream>>>(nullptr, nullptr, wl1_, wB, wd_, wbias, w0_, 4096, 1024, 64);

  // a LoRA: (xa@A^T) -> sigmoid(@B^T + bias)
  gemm_k<A_MIX, EPI_BF16><<<gN64, blk, 0, stream>>>(x, x_a, nullptr, aA, al1_, nullptr, nullptr, 4096, 64, 1024);
  gemm_k<A_BF16, EPI_SIGBIAS_F32><<<gBig, blk, 0, stream>>>(nullptr, nullptr, al1_, aB, ab_, abias, nullptr, 4096, 1024, 64);

  // g LoRA: sigmoid(xg@A^T) -> @B^T
  gemm_k<A_MIX, EPI_SIG_BF16><<<gN160, blk, 0, stream>>>(x, x_g, nullptr, gA, gl1_, nullptr, nullptr, 4096, 160, 1024);
  gemm_k<A_BF16, EPI_F32><<<gBig, blk, 0, stream>>>(nullptr, nullptr, gl1_, gB, g_, nullptr, nullptr, 4096, 1024, 160);

  // kk normalize + k scale + b
  kkprep_k<<<dim3(16384), blk, 0, stream>>>(k_, ab_, kk_, k_k, k_a);

  // sequential recurrence (row-parallel, depth-8 pipelined)
  scan_k<<<dim3(512), dim3(64), 0, stream>>>(r_, wd_, k_, v_, ab_, kk_, o_);

  // GroupNorm + bonus + gate
  gnout_k<<<dim3(16384), blk, 0, stream>>>(o_, r_, k_, v_, g_, r_k, gnw, gnb, y_);

  // output projection
  gemm_k<A_BF16, EPI_F32><<<gBig, blk, 0, stream>>>(nullptr, nullptr, y_, Wo, (float*)d_out, nullptr, nullptr, 4096, 1024, 1024);
}